// Round 2
// baseline (625.846 us; speedup 1.0000x reference)
//
#include <hip/hip_runtime.h>
#include <stdint.h>

// Superpoint pooling via 29-bit key bitmap + prefix-popcount ranking.
// key = batch(2b) | qx(9b) | qy(9b) | qz(9b); numeric order == lexicographic order,
// so exclusive prefix popcount over the presence bitmap == jnp.unique sorted rank.
// k5 does the fused features+MLP with MFMA in fragment layout (coalesced 64B groups).

static constexpr uint32_t NWORDS = 1u << 24;   // 2^29 bits / 32

typedef __attribute__((ext_vector_type(8))) short short8;
typedef __attribute__((ext_vector_type(4))) float f32x4;

__device__ __forceinline__ short f2bf(float x) {
    union { float f; uint32_t u; } v; v.f = x;
    uint32_t u = v.u;
    uint32_t r = (u + 0x7FFFu + ((u >> 16) & 1u)) >> 16;   // RNE
    return (short)r;
}

__device__ __forceinline__ uint32_t point_key(float4 c) {
    uint32_t b  = (uint32_t)(int)c.x;
    uint32_t qx = (uint32_t)(int)floorf(c.y / 0.1f);
    uint32_t qy = (uint32_t)(int)floorf(c.z / 0.1f);
    uint32_t qz = (uint32_t)(int)floorf(c.w / 0.1f);
    return (b << 27) | (qx << 18) | (qy << 9) | qz;
}

__global__ void k1_keys(const float4* __restrict__ coords, uint32_t* __restrict__ keys,
                        uint32_t* __restrict__ bitmap, int N) {
    int i = blockIdx.x * blockDim.x + threadIdx.x;
    if (i >= N) return;
    uint32_t key = point_key(coords[i]);
    keys[i] = key;
    atomicOr(&bitmap[key >> 5], 1u << (key & 31u));
}

// Per-256-word block popcount scan: per-8-word exclusive prefix (u16) + block total.
__global__ void k2a_blockscan(const uint32_t* __restrict__ bitmap,
                              uint16_t* __restrict__ scan8,
                              uint32_t* __restrict__ bsum) {
    __shared__ uint32_t s[256];
    int t = threadIdx.x;
    uint32_t w = blockIdx.x * 256u + t;
    uint32_t pc = __popc(bitmap[w]);
    s[t] = pc;
    __syncthreads();
    for (int off = 1; off < 256; off <<= 1) {
        uint32_t v = (t >= off) ? s[t - off] : 0u;
        __syncthreads();
        s[t] += v;
        __syncthreads();
    }
    if ((t & 7) == 0) scan8[w >> 3] = (uint16_t)(s[t] - pc);
    if (t == 255) bsum[blockIdx.x] = s[255];
}

// Exclusive scan of 65536 block sums; bscan[65536] = total unique count U.
__global__ void k2b_topscan(const uint32_t* __restrict__ bsum, uint32_t* __restrict__ bscan) {
    __shared__ uint32_t s[1024];
    int t = threadIdx.x;
    uint32_t base = (uint32_t)t * 64u;
    uint32_t sum = 0;
    for (int k = 0; k < 64; ++k) sum += bsum[base + k];
    s[t] = sum;
    __syncthreads();
    for (int off = 1; off < 1024; off <<= 1) {
        uint32_t v = (t >= off) ? s[t - off] : 0u;
        __syncthreads();
        s[t] += v;
        __syncthreads();
    }
    uint32_t run = s[t] - sum;
    for (int k = 0; k < 64; ++k) { bscan[base + k] = run; run += bsum[base + k]; }
    if (t == 1023) bscan[65536] = run;
}

__global__ void k3_rank(const float4* __restrict__ coords,
                        uint32_t* __restrict__ keys,   // in: keys, out: ranks
                        const uint32_t* __restrict__ bitmap,
                        const uint16_t* __restrict__ scan8,
                        const uint32_t* __restrict__ bscan,
                        float* __restrict__ sums,      // [N][4] = {count, x, y, z}
                        float* __restrict__ out_sp, int N) {
    int i = blockIdx.x * blockDim.x + threadIdx.x;
    if (i >= N) return;
    uint32_t key = keys[i];
    uint32_t w = key >> 5, bit = key & 31u;
    uint32_t g = w & ~7u;
    const uint4* bm4 = (const uint4*)(bitmap + g);
    uint4 lo = bm4[0], hi = bm4[1];
    uint32_t wd[8] = {lo.x, lo.y, lo.z, lo.w, hi.x, hi.y, hi.z, hi.w};
    uint32_t idx = w & 7u;
    uint32_t r = bscan[w >> 8] + (uint32_t)scan8[w >> 3];
    uint32_t cur = 0;
    #pragma unroll
    for (uint32_t j = 0; j < 8; ++j) {
        r += (j < idx) ? __popc(wd[j]) : 0u;
        cur = (j == idx) ? wd[j] : cur;
    }
    r += __popc(cur & ((1u << bit) - 1u));
    keys[i] = r;
    out_sp[i] = (float)r;
    float4 c = coords[i];
    float* s4 = sums + 4u * (size_t)r;
    atomicAdd(s4 + 0, 1.0f);
    atomicAdd(s4 + 1, c.y);
    atomicAdd(s4 + 2, c.z);
    atomicAdd(s4 + 3, c.w);
}

// Scalar MLP for the rare multi-point voxels (~0.1%).
__device__ __forceinline__ void mlp_add(float cx, float cy, float cz,
        const float* __restrict__ W1, const float* __restrict__ b1,
        const float* __restrict__ W2, const float* __restrict__ b2,
        float out[64]) {
    #pragma unroll
    for (int j = 0; j < 64; ++j) out[j] += b2[j];
    #pragma unroll 1
    for (int k = 0; k < 64; ++k) {
        float hk = fmaxf(b1[k] + cx * W1[k] + cy * W1[64 + k] + cz * W1[128 + k], 0.0f);
        #pragma unroll
        for (int j = 0; j < 64; ++j) out[j] = fmaf(hk, W2[64 * k + j], out[j]);
    }
}

__global__ __launch_bounds__(256) void k4_centers(
        const float4* __restrict__ sums,
        const float* __restrict__ W1, const float* __restrict__ b1,
        const float* __restrict__ W2, const float* __restrict__ b2,
        float* __restrict__ out_feat, float* __restrict__ out_cent, int N) {
    int r = blockIdx.x * blockDim.x + threadIdx.x;
    if (r >= N) return;
    float4 s = sums[r];
    float c = s.x;
    if (c == 0.0f) {
        float4 z = make_float4(0.f, 0.f, 0.f, 0.f);
        float4* fr = (float4*)(out_feat + (size_t)r * 64);
        #pragma unroll
        for (int q = 0; q < 16; ++q) fr[q] = z;
        out_cent[3 * (size_t)r + 0] = 0.f;
        out_cent[3 * (size_t)r + 1] = 0.f;
        out_cent[3 * (size_t)r + 2] = 0.f;
        return;
    }
    float inv = 1.0f / c;
    float cx = s.y * inv, cy = s.z * inv, cz = s.w * inv;
    out_cent[3 * (size_t)r + 0] = cx;
    out_cent[3 * (size_t)r + 1] = cy;
    out_cent[3 * (size_t)r + 2] = cz;
    if (c > 1.5f) {   // rare: write pos; k5 atomic-adds f/c on top
        float out[64];
        #pragma unroll
        for (int j = 0; j < 64; ++j) out[j] = 0.f;
        mlp_add(cx, cy, cz, W1, b1, W2, b2, out);
        float* fr = out_feat + (size_t)r * 64;
        #pragma unroll
        for (int j = 0; j < 64; ++j) fr[j] = out[j];
    }
}

// One wave = 64 rows. pos = relu(c@W1+b1)@W2+b2 via 32x mfma_f32_16x16x32_bf16.
// A-frag (h): lane l supplies h[l&15][(l>>4)*8+j], computed in-place from shuffled xyz.
// B-frag (W2): lane l supplies W2[(l>>4)*8+j][l&15] per 16-col group.
// D-frag: col=lane&15, row=(lane>>4)*4+reg (HW-verified) -> 16-lane/64B coalesced
// feature loads + output stores for singleton voxels; multi voxels use atomics.
__global__ __launch_bounds__(256) void k5_features(
        const float4* __restrict__ coords, const float* __restrict__ features,
        const uint32_t* __restrict__ ranks, const float4* __restrict__ sums,
        const float* __restrict__ W1, const float* __restrict__ b1,
        const float* __restrict__ W2, const float* __restrict__ b2,
        float* __restrict__ out_feat, int N) {
    int lane = threadIdx.x & 63;
    int rows_base = blockIdx.x * 256 + (threadIdx.x >> 6) * 64;
    int my_row = rows_base + lane;
    int icl = my_row < N ? my_row : N - 1;

    float4 c4 = coords[icl];
    uint32_t r = ranks[icl];
    float cnt = sums[r].x;

    // xyz of the 16 rows this lane's A-fragments cover, per row-group g
    float scx[4], scy[4], scz[4];
    #pragma unroll
    for (int g = 0; g < 4; ++g) {
        int src = (g << 4) | (lane & 15);
        scx[g] = __shfl(c4.y, src);
        scy[g] = __shfl(c4.z, src);
        scz[g] = __shfl(c4.w, src);
    }

    f32x4 acc[4][4];
    #pragma unroll
    for (int cg = 0; cg < 4; ++cg) {
        float b2c = b2[(cg << 4) | (lane & 15)];
        #pragma unroll
        for (int g = 0; g < 4; ++g)
            acc[g][cg] = (f32x4){b2c, b2c, b2c, b2c};
    }

    #pragma unroll
    for (int s = 0; s < 2; ++s) {
        int kb = s * 32 + ((lane >> 4) << 3);
        float4 tx0 = *(const float4*)(W1 + kb),        tx1 = *(const float4*)(W1 + kb + 4);
        float4 ty0 = *(const float4*)(W1 + 64 + kb),   ty1 = *(const float4*)(W1 + 64 + kb + 4);
        float4 tz0 = *(const float4*)(W1 + 128 + kb),  tz1 = *(const float4*)(W1 + 128 + kb + 4);
        float4 tb0 = *(const float4*)(b1 + kb),        tb1 = *(const float4*)(b1 + kb + 4);
        float w1x[8] = {tx0.x, tx0.y, tx0.z, tx0.w, tx1.x, tx1.y, tx1.z, tx1.w};
        float w1y[8] = {ty0.x, ty0.y, ty0.z, ty0.w, ty1.x, ty1.y, ty1.z, ty1.w};
        float w1z[8] = {tz0.x, tz0.y, tz0.z, tz0.w, tz1.x, tz1.y, tz1.z, tz1.w};
        float b1v[8] = {tb0.x, tb0.y, tb0.z, tb0.w, tb1.x, tb1.y, tb1.z, tb1.w};

        short8 bfrag[4];
        #pragma unroll
        for (int cg = 0; cg < 4; ++cg) {
            int col = (cg << 4) | (lane & 15);
            #pragma unroll
            for (int j = 0; j < 8; ++j)
                bfrag[cg][j] = f2bf(W2[(size_t)(kb + j) * 64 + col]);
        }

        #pragma unroll
        for (int g = 0; g < 4; ++g) {
            short8 af;
            #pragma unroll
            for (int j = 0; j < 8; ++j) {
                float h = b1v[j];
                h = fmaf(scx[g], w1x[j], h);
                h = fmaf(scy[g], w1y[j], h);
                h = fmaf(scz[g], w1z[j], h);
                af[j] = f2bf(fmaxf(h, 0.0f));
            }
            #pragma unroll
            for (int cg = 0; cg < 4; ++cg)
                acc[g][cg] = __builtin_amdgcn_mfma_f32_16x16x32_bf16(af, bfrag[cg], acc[g][cg], 0, 0, 0);
        }
    }

    // Epilogue: singleton rows -> features + pos, stored in D-fragment layout.
    #pragma unroll
    for (int g = 0; g < 4; ++g) {
        #pragma unroll
        for (int q = 0; q < 4; ++q) {
            int rl = (g << 4) + ((lane >> 4) << 2) + q;
            uint32_t rr = (uint32_t)__shfl((int)r, rl);
            float cq = __shfl(cnt, rl);
            int rowg = rows_base + rl;
            if (rowg < N && cq == 1.0f) {
                #pragma unroll
                for (int cg = 0; cg < 4; ++cg) {
                    int col = (cg << 4) | (lane & 15);
                    float val = acc[g][cg][q] + features[(size_t)rowg * 64 + col];
                    out_feat[(size_t)rr * 64 + col] = val;
                }
            }
        }
    }

    // Multi-point voxels: atomic accumulate f/c (rare).
    if (my_row < N && cnt > 1.5f) {
        float inv = 1.0f / cnt;
        const float* frow = features + (size_t)my_row * 64;
        float* orow = out_feat + (size_t)r * 64;
        #pragma unroll 1
        for (int q = 0; q < 64; ++q) atomicAdd(&orow[q], frow[q] * inv);
    }
}

__global__ void k6_offsets(const uint32_t* __restrict__ bscan, float* __restrict__ out_off) {
    int t = threadIdx.x;
    if (t < 5) {
        uint32_t v;
        if (t == 0)      v = 0u;
        else if (t == 4) v = bscan[65536];
        else             v = bscan[(uint32_t)t << 14];   // rank at key b<<27
        out_off[t] = (float)v;
    }
}

extern "C" void kernel_launch(void* const* d_in, const int* in_sizes, int n_in,
                              void* d_out, int out_size, void* d_ws, size_t ws_size,
                              hipStream_t stream) {
    const float4* coords = (const float4*)d_in[0];
    const float*  feats  = (const float*)d_in[1];
    const float*  W1 = (const float*)d_in[2];
    const float*  b1 = (const float*)d_in[3];
    const float*  W2 = (const float*)d_in[4];
    const float*  b2 = (const float*)d_in[5];
    int N = in_sizes[0] / 4;

    char* ws = (char*)d_ws;
    uint32_t* bitmap = (uint32_t*)ws;                                  // 64 MB
    uint16_t* scan8  = (uint16_t*)(ws + (1u << 26));                   // 4 MB
    uint32_t* bsum   = (uint32_t*)(ws + (1u << 26) + (1u << 22));      // 256 KB
    uint32_t* bscan  = bsum + 65536;                                   // 65537 u32
    size_t off = (size_t)(1u << 26) + (1u << 22) + (size_t)65536 * 4 + (size_t)65537 * 4;
    off = (off + 15) & ~(size_t)15;
    uint32_t* keys = (uint32_t*)(ws + off);                            // 4N B (keys->ranks)
    size_t off2 = (off + (size_t)N * 4 + 15) & ~(size_t)15;
    float* sums = (float*)(ws + off2);                                 // 16N B {cnt,x,y,z}

    float* out_feat = (float*)d_out;
    float* out_cent = out_feat + (size_t)N * 64;
    float* out_sp   = out_cent + (size_t)N * 3;
    float* out_off  = out_sp + N;

    hipMemsetAsync(bitmap, 0, (size_t)NWORDS * 4u, stream);
    hipMemsetAsync(sums, 0, (size_t)N * 16u, stream);

    int nb = (N + 255) / 256;
    k1_keys<<<nb, 256, 0, stream>>>(coords, keys, bitmap, N);
    k2a_blockscan<<<NWORDS / 256, 256, 0, stream>>>(bitmap, scan8, bsum);
    k2b_topscan<<<1, 1024, 0, stream>>>(bsum, bscan);
    k3_rank<<<nb, 256, 0, stream>>>(coords, keys, bitmap, scan8, bscan, sums, out_sp, N);
    k4_centers<<<nb, 256, 0, stream>>>((const float4*)sums, W1, b1, W2, b2, out_feat, out_cent, N);
    k5_features<<<nb, 256, 0, stream>>>(coords, feats, keys, (const float4*)sums,
                                        W1, b1, W2, b2, out_feat, N);
    k6_offsets<<<1, 64, 0, stream>>>(bscan, out_off);
}

// Round 3
// 617.976 us; speedup vs baseline: 1.0127x; 1.0127x over previous
//
#include <hip/hip_runtime.h>
#include <stdint.h>

// Superpoint pooling via 29-bit key bitmap + prefix-popcount ranking.
// key = batch(2b)|qx(9b)|qy(9b)|qz(9b); numeric order == lex order, so exclusive
// prefix popcount over the presence bitmap == jnp.unique sorted rank.
// R3: rank-centric fused epilogue -> sequential out_feat writes, gather reads.

static constexpr uint32_t NWORDS = 1u << 24;   // 2^29 bits / 32

typedef __attribute__((ext_vector_type(8))) short short8;
typedef __attribute__((ext_vector_type(4))) float f32x4;

__device__ __forceinline__ short f2bf(float x) {
    union { float f; uint32_t u; } v; v.f = x;
    uint32_t u = v.u;
    uint32_t r = (u + 0x7FFFu + ((u >> 16) & 1u)) >> 16;   // RNE
    return (short)r;
}

__device__ __forceinline__ uint32_t point_key(float4 c) {
    uint32_t b  = (uint32_t)(int)c.x;
    uint32_t qx = (uint32_t)(int)floorf(c.y / 0.1f);
    uint32_t qy = (uint32_t)(int)floorf(c.z / 0.1f);
    uint32_t qz = (uint32_t)(int)floorf(c.w / 0.1f);
    return (b << 27) | (qx << 18) | (qy << 9) | qz;
}

// W2 -> bf16, transposed: W2T[col*64+k] = bf16(W2[k*64+col]); B-frags become 16B loads.
__global__ void k0_w2t(const float* __restrict__ W2, short* __restrict__ W2T) {
    int t = blockIdx.x * 256 + threadIdx.x;
    if (t < 4096) {
        int col = t >> 6, k = t & 63;
        W2T[col * 64 + k] = f2bf(W2[k * 64 + col]);
    }
}

__global__ void k1_keys(const float4* __restrict__ coords, uint32_t* __restrict__ keys,
                        uint32_t* __restrict__ bitmap, int N) {
    int i = blockIdx.x * blockDim.x + threadIdx.x;
    if (i >= N) return;
    uint32_t key = point_key(coords[i]);
    keys[i] = key;
    atomicOr(&bitmap[key >> 5], 1u << (key & 31u));
}

// Per-256-word block popcount scan: per-8-word exclusive prefix (u16) + block total.
__global__ void k2a_blockscan(const uint32_t* __restrict__ bitmap,
                              uint16_t* __restrict__ scan8,
                              uint32_t* __restrict__ bsum) {
    __shared__ uint32_t s[256];
    int t = threadIdx.x;
    uint32_t w = blockIdx.x * 256u + t;
    uint32_t pc = __popc(bitmap[w]);
    s[t] = pc;
    __syncthreads();
    for (int off = 1; off < 256; off <<= 1) {
        uint32_t v = (t >= off) ? s[t - off] : 0u;
        __syncthreads();
        s[t] += v;
        __syncthreads();
    }
    if ((t & 7) == 0) scan8[w >> 3] = (uint16_t)(s[t] - pc);
    if (t == 255) bsum[blockIdx.x] = s[255];
}

// Exclusive scan of 65536 block sums; bscan[65536] = total unique count U.
__global__ void k2b_topscan(const uint32_t* __restrict__ bsum, uint32_t* __restrict__ bscan) {
    __shared__ uint32_t s[1024];
    int t = threadIdx.x;
    uint32_t base = (uint32_t)t * 64u;
    const uint4* b4 = (const uint4*)(bsum + base);
    uint32_t sum = 0;
    #pragma unroll
    for (int k = 0; k < 16; ++k) { uint4 v = b4[k]; sum += v.x + v.y + v.z + v.w; }
    s[t] = sum;
    __syncthreads();
    for (int off = 1; off < 1024; off <<= 1) {
        uint32_t v = (t >= off) ? s[t - off] : 0u;
        __syncthreads();
        s[t] += v;
        __syncthreads();
    }
    uint32_t run = s[t] - sum;
    for (int k = 0; k < 64; ++k) { bscan[base + k] = run; run += bsum[base + k]; }
    if (t == 1023) bscan[65536] = run;
}

__global__ void k3_rank(const float4* __restrict__ coords,
                        uint32_t* __restrict__ keys,   // in: keys, out: ranks
                        const uint32_t* __restrict__ bitmap,
                        const uint16_t* __restrict__ scan8,
                        const uint32_t* __restrict__ bscan,
                        float* __restrict__ sums,      // [N][4] = {count, x, y, z}
                        uint32_t* __restrict__ inv,    // rank -> point (valid when cnt==1)
                        float* __restrict__ out_sp, int N) {
    int i = blockIdx.x * blockDim.x + threadIdx.x;
    if (i >= N) return;
    uint32_t key = keys[i];
    uint32_t w = key >> 5, bit = key & 31u;
    const uint4* bm4 = (const uint4*)(bitmap + (w & ~7u));
    uint4 lo = bm4[0], hi = bm4[1];
    uint32_t wd[8] = {lo.x, lo.y, lo.z, lo.w, hi.x, hi.y, hi.z, hi.w};
    uint32_t idx = w & 7u;
    uint32_t r = bscan[w >> 8] + (uint32_t)scan8[w >> 3];
    uint32_t cur = 0;
    #pragma unroll
    for (uint32_t j = 0; j < 8; ++j) {
        r += (j < idx) ? __popc(wd[j]) : 0u;
        cur = (j == idx) ? wd[j] : cur;
    }
    r += __popc(cur & ((1u << bit) - 1u));
    keys[i] = r;
    inv[r] = (uint32_t)i;
    out_sp[i] = (float)r;
    float4 c = coords[i];
    float* s4 = sums + 4u * (size_t)r;
    atomicAdd(s4 + 0, 1.0f);
    atomicAdd(s4 + 1, c.y);
    atomicAdd(s4 + 2, c.z);
    atomicAdd(s4 + 3, c.w);
}

// Rank-centric fused epilogue. One wave = 64 consecutive ranks.
// pos = relu(c@W1+b1)@W2+b2 via 32x mfma_f32_16x16x32_bf16 (layouts verified in R2).
// A-frag: lane supplies h[row=l&15][k=(l>>4)*8+j] per 16-row group (centers via cached loads).
// B-frag: single short8 load from pre-transposed W2T.
// D-frag: col=lane&15, row=(lane>>4)*4+reg. Stores are dense/streaming; feature
// gathers are random 256B-granule reads (only for singleton ranks).
__global__ __launch_bounds__(256) void k5_fused(
        const float* __restrict__ features,
        const uint32_t* __restrict__ inv,
        const float4* __restrict__ sums,
        const float* __restrict__ W1, const float* __restrict__ b1,
        const short* __restrict__ W2T, const float* __restrict__ b2,
        float* __restrict__ out_feat, float* __restrict__ out_cent, int N) {
    int lane = threadIdx.x & 63;
    int rows_base = blockIdx.x * 256 + (threadIdx.x >> 6) * 64;

    // centers output for own rank (sums==0 when invalid -> writes 0, matching ref)
    int my = rows_base + lane;
    if (my < N) {
        float4 s4 = sums[my];
        float ic = s4.x > 0.f ? 1.f / s4.x : 0.f;
        out_cent[3 * (size_t)my + 0] = s4.y * ic;
        out_cent[3 * (size_t)my + 1] = s4.z * ic;
        out_cent[3 * (size_t)my + 2] = s4.w * ic;
    }

    // centers for the 16 rows this lane's A-fragments cover (L1-hot re-loads)
    float scx[4], scy[4], scz[4];
    #pragma unroll
    for (int g = 0; g < 4; ++g) {
        int rg = rows_base + (g << 4) + (lane & 15);
        float4 sg = sums[rg < N ? rg : N - 1];
        float ic = sg.x > 0.f ? 1.f / sg.x : 0.f;
        scx[g] = sg.y * ic; scy[g] = sg.z * ic; scz[g] = sg.w * ic;
    }

    f32x4 acc[4][4];
    #pragma unroll
    for (int cg = 0; cg < 4; ++cg) {
        float b2c = b2[(cg << 4) | (lane & 15)];
        #pragma unroll
        for (int g = 0; g < 4; ++g)
            acc[g][cg] = (f32x4){b2c, b2c, b2c, b2c};
    }

    #pragma unroll
    for (int s = 0; s < 2; ++s) {
        int kb = s * 32 + ((lane >> 4) << 3);
        float4 tx0 = *(const float4*)(W1 + kb),       tx1 = *(const float4*)(W1 + kb + 4);
        float4 ty0 = *(const float4*)(W1 + 64 + kb),  ty1 = *(const float4*)(W1 + 64 + kb + 4);
        float4 tz0 = *(const float4*)(W1 + 128 + kb), tz1 = *(const float4*)(W1 + 128 + kb + 4);
        float4 tb0 = *(const float4*)(b1 + kb),       tb1 = *(const float4*)(b1 + kb + 4);
        float w1x[8] = {tx0.x, tx0.y, tx0.z, tx0.w, tx1.x, tx1.y, tx1.z, tx1.w};
        float w1y[8] = {ty0.x, ty0.y, ty0.z, ty0.w, ty1.x, ty1.y, ty1.z, ty1.w};
        float w1z[8] = {tz0.x, tz0.y, tz0.z, tz0.w, tz1.x, tz1.y, tz1.z, tz1.w};
        float b1v[8] = {tb0.x, tb0.y, tb0.z, tb0.w, tb1.x, tb1.y, tb1.z, tb1.w};

        short8 bfrag[4];
        #pragma unroll
        for (int cg = 0; cg < 4; ++cg) {
            int col = (cg << 4) | (lane & 15);
            bfrag[cg] = *(const short8*)(W2T + col * 64 + kb);
        }

        #pragma unroll
        for (int g = 0; g < 4; ++g) {
            short8 af;
            #pragma unroll
            for (int j = 0; j < 8; ++j) {
                float h = fmaf(scz[g], w1z[j], fmaf(scy[g], w1y[j], fmaf(scx[g], w1x[j], b1v[j])));
                af[j] = f2bf(fmaxf(h, 0.0f));
            }
            #pragma unroll
            for (int cg = 0; cg < 4; ++cg)
                acc[g][cg] = __builtin_amdgcn_mfma_f32_16x16x32_bf16(af, bfrag[cg], acc[g][cg], 0, 0, 0);
        }
    }

    // Epilogue: per fragment row gr -> cnt predicate {0: zero, 1: +features[inv], >1: pos only}
    #pragma unroll
    for (int g = 0; g < 4; ++g) {
        #pragma unroll
        for (int q = 0; q < 4; ++q) {
            int gr = rows_base + (g << 4) + ((lane >> 4) << 2) + q;
            if (gr >= N) continue;
            float cntg = sums[gr].x;     // uniform within 16-lane group, cached
            float vals[4];
            #pragma unroll
            for (int cg = 0; cg < 4; ++cg) vals[cg] = acc[g][cg][q];
            if (cntg == 0.0f) {
                #pragma unroll
                for (int cg = 0; cg < 4; ++cg) vals[cg] = 0.0f;
            } else if (cntg == 1.0f) {
                size_t fb = (size_t)inv[gr] * 64;
                #pragma unroll
                for (int cg = 0; cg < 4; ++cg)
                    vals[cg] += features[fb + (cg << 4) + (lane & 15)];
            }
            size_t ob = (size_t)gr * 64;
            #pragma unroll
            for (int cg = 0; cg < 4; ++cg)
                out_feat[ob + (cg << 4) + (lane & 15)] = vals[cg];
        }
    }
}

// Multi-point voxels (~0.1%): atomic accumulate f/c on top of pos.
__global__ __launch_bounds__(256) void k5b_multi(
        const float* __restrict__ features, const uint32_t* __restrict__ ranks,
        const float4* __restrict__ sums, float* __restrict__ out_feat, int N) {
    int i = blockIdx.x * blockDim.x + threadIdx.x;
    if (i >= N) return;
    uint32_t r = ranks[i];
    float cnt = sums[r].x;
    if (cnt > 1.5f) {
        float iv = 1.0f / cnt;
        const float* frow = features + (size_t)i * 64;
        float* orow = out_feat + (size_t)r * 64;
        #pragma unroll 1
        for (int q = 0; q < 64; ++q) atomicAdd(&orow[q], frow[q] * iv);
    }
}

__global__ void k6_offsets(const uint32_t* __restrict__ bscan, float* __restrict__ out_off) {
    int t = threadIdx.x;
    if (t < 5) {
        uint32_t v;
        if (t == 0)      v = 0u;
        else if (t == 4) v = bscan[65536];
        else             v = bscan[(uint32_t)t << 14];   // rank at key b<<27
        out_off[t] = (float)v;
    }
}

extern "C" void kernel_launch(void* const* d_in, const int* in_sizes, int n_in,
                              void* d_out, int out_size, void* d_ws, size_t ws_size,
                              hipStream_t stream) {
    const float4* coords = (const float4*)d_in[0];
    const float*  feats  = (const float*)d_in[1];
    const float*  W1 = (const float*)d_in[2];
    const float*  b1 = (const float*)d_in[3];
    const float*  W2 = (const float*)d_in[4];
    const float*  b2 = (const float*)d_in[5];
    int N = in_sizes[0] / 4;

    char* ws = (char*)d_ws;
    uint32_t* bitmap = (uint32_t*)ws;                                  // 64 MB
    uint16_t* scan8  = (uint16_t*)(ws + (1u << 26));                   // 4 MB
    uint32_t* bsum   = (uint32_t*)(ws + (1u << 26) + (1u << 22));      // 256 KB
    uint32_t* bscan  = bsum + 65536;                                   // 65537 u32
    size_t off = (size_t)(1u << 26) + (1u << 22) + (size_t)65536 * 4 + (size_t)65537 * 4;
    off = (off + 15) & ~(size_t)15;
    uint32_t* keys = (uint32_t*)(ws + off);                            // 4N (keys->ranks)
    size_t off2 = (off + (size_t)N * 4 + 15) & ~(size_t)15;
    float* sums = (float*)(ws + off2);                                 // 16N {cnt,x,y,z}
    size_t off3 = off2 + (size_t)N * 16;
    uint32_t* inv = (uint32_t*)(ws + off3);                            // 4N rank->point
    size_t off4 = (off3 + (size_t)N * 4 + 15) & ~(size_t)15;
    short* W2T = (short*)(ws + off4);                                  // 8 KB bf16 W2^T

    float* out_feat = (float*)d_out;
    float* out_cent = out_feat + (size_t)N * 64;
    float* out_sp   = out_cent + (size_t)N * 3;
    float* out_off  = out_sp + N;

    hipMemsetAsync(bitmap, 0, (size_t)NWORDS * 4u, stream);
    hipMemsetAsync(sums, 0, (size_t)N * 16u, stream);

    int nb = (N + 255) / 256;
    k0_w2t<<<16, 256, 0, stream>>>(W2, W2T);
    k1_keys<<<nb, 256, 0, stream>>>(coords, keys, bitmap, N);
    k2a_blockscan<<<NWORDS / 256, 256, 0, stream>>>(bitmap, scan8, bsum);
    k2b_topscan<<<1, 1024, 0, stream>>>(bsum, bscan);
    k3_rank<<<nb, 256, 0, stream>>>(coords, keys, bitmap, scan8, bscan, sums, inv, out_sp, N);
    k5_fused<<<nb, 256, 0, stream>>>(feats, inv, (const float4*)sums, W1, b1, W2T, b2,
                                     out_feat, out_cent, N);
    k5b_multi<<<nb, 256, 0, stream>>>(feats, keys, (const float4*)sums, out_feat, N);
    k6_offsets<<<1, 64, 0, stream>>>(bscan, out_off);
}

// Round 4
// 353.944 us; speedup vs baseline: 1.7682x; 1.7460x over previous
//
#include <hip/hip_runtime.h>
#include <stdint.h>

// Superpoint pooling via 29-bit key bitmap + prefix-popcount ranking.
// key = batch(2b)|qx(9b)|qy(9b)|qz(9b); numeric order == lex order, so exclusive
// prefix popcount over the presence bitmap == jnp.unique sorted rank.
// R4: transposed MFMA (P^T) -> float4 epilogue; 1-atomic k3 with multi fixup;
// wave-shuffle bitmap scan (1024 words/block).

static constexpr uint32_t NWORDS = 1u << 24;   // 2^29 bits / 32
static constexpr uint32_t NBLK   = NWORDS / 1024;   // 16384 scan blocks

typedef __attribute__((ext_vector_type(8))) short short8;
typedef __attribute__((ext_vector_type(4))) float f32x4;

__device__ __forceinline__ short f2bf(float x) {
    union { float f; uint32_t u; } v; v.f = x;
    uint32_t u = v.u;
    uint32_t r = (u + 0x7FFFu + ((u >> 16) & 1u)) >> 16;   // RNE
    return (short)r;
}

__device__ __forceinline__ uint32_t point_key(float4 c) {
    uint32_t b  = (uint32_t)(int)c.x;
    uint32_t qx = (uint32_t)(int)floorf(c.y / 0.1f);
    uint32_t qy = (uint32_t)(int)floorf(c.z / 0.1f);
    uint32_t qz = (uint32_t)(int)floorf(c.w / 0.1f);
    return (b << 27) | (qx << 18) | (qy << 9) | qz;
}

// W2 -> bf16, transposed: W2T[col*64+k] = bf16(W2[k*64+col]).
__global__ void k0_w2t(const float* __restrict__ W2, short* __restrict__ W2T) {
    int t = blockIdx.x * 256 + threadIdx.x;
    if (t < 4096) {
        int col = t >> 6, k = t & 63;
        W2T[col * 64 + k] = f2bf(W2[k * 64 + col]);
    }
}

__global__ void k1_keys(const float4* __restrict__ coords, uint32_t* __restrict__ bitmap, int N) {
    int i = blockIdx.x * blockDim.x + threadIdx.x;
    if (i >= N) return;
    uint32_t key = point_key(coords[i]);
    atomicOr(&bitmap[key >> 5], 1u << (key & 31u));
}

// 1024 words/block, 256 threads (4 words/thread via uint4), wave-shuffle scan.
// scan8[g]: exclusive popcount prefix within block at 8-word granularity (<=32512, fits u16).
__global__ __launch_bounds__(256) void k2a_blockscan(
        const uint4* __restrict__ bm4, uint16_t* __restrict__ scan8,
        uint32_t* __restrict__ bsum) {
    int t = threadIdx.x;
    int lane = t & 63, wid = t >> 6;
    uint4 v = bm4[(size_t)blockIdx.x * 256 + t];
    uint32_t pc = __popc(v.x) + __popc(v.y) + __popc(v.z) + __popc(v.w);
    uint32_t sc = pc;
    #pragma unroll
    for (int off = 1; off < 64; off <<= 1) {
        uint32_t n = __shfl_up(sc, off);
        if (lane >= off) sc += n;
    }
    __shared__ uint32_t wt[4];
    if (lane == 63) wt[wid] = sc;
    __syncthreads();
    uint32_t wbase = 0;
    #pragma unroll
    for (int w = 0; w < 4; ++w) wbase += (w < wid) ? wt[w] : 0u;
    uint32_t excl = wbase + sc - pc;
    if (!(t & 1)) scan8[(size_t)blockIdx.x * 128 + (t >> 1)] = (uint16_t)excl;
    if (t == 255) bsum[blockIdx.x] = wbase + sc;
}

// Exclusive scan of 16384 block sums; bscan[16384] = total unique count U.
__global__ void k2b_topscan(const uint32_t* __restrict__ bsum, uint32_t* __restrict__ bscan) {
    __shared__ uint32_t s[1024];
    int t = threadIdx.x;
    uint32_t base = (uint32_t)t * 16u;
    const uint4* b4 = (const uint4*)(bsum + base);
    uint32_t sum = 0;
    #pragma unroll
    for (int k = 0; k < 4; ++k) { uint4 v = b4[k]; sum += v.x + v.y + v.z + v.w; }
    s[t] = sum;
    __syncthreads();
    for (int off = 1; off < 1024; off <<= 1) {
        uint32_t v = (t >= off) ? s[t - off] : 0u;
        __syncthreads();
        s[t] += v;
        __syncthreads();
    }
    uint32_t run = s[t] - sum;
    for (int k = 0; k < 16; ++k) { bscan[base + k] = run; run += bsum[base + k]; }
    if (t == 1023) bscan[16384] = run;
}

// Rank each point. ONE atomic (count in sums.x) + plain 12B store of own xyz
// (exact for singletons; multi rows fixed by k3b/k3c).
__global__ void k3a_rank(const float4* __restrict__ coords,
                         uint32_t* __restrict__ ranks,
                         const uint32_t* __restrict__ bitmap,
                         const uint16_t* __restrict__ scan8,
                         const uint32_t* __restrict__ bscan,
                         float* __restrict__ sums,      // [N][4] = {count, x, y, z}
                         uint32_t* __restrict__ inv,    // rank -> point
                         float* __restrict__ out_sp, int N) {
    int i = blockIdx.x * blockDim.x + threadIdx.x;
    if (i >= N) return;
    float4 c = coords[i];
    uint32_t key = point_key(c);
    uint32_t w = key >> 5, bit = key & 31u;
    const uint4* bm4 = (const uint4*)(bitmap + (w & ~7u));
    uint4 lo = bm4[0], hi = bm4[1];
    uint32_t wd[8] = {lo.x, lo.y, lo.z, lo.w, hi.x, hi.y, hi.z, hi.w};
    uint32_t idx = w & 7u;
    uint32_t r = bscan[w >> 10] + (uint32_t)scan8[w >> 3];
    uint32_t cur = 0;
    #pragma unroll
    for (uint32_t j = 0; j < 8; ++j) {
        r += (j < idx) ? __popc(wd[j]) : 0u;
        cur = (j == idx) ? wd[j] : cur;
    }
    r += __popc(cur & ((1u << bit) - 1u));
    ranks[i] = r;
    inv[r] = (uint32_t)i;
    out_sp[i] = (float)r;
    float* s4 = sums + 4u * (size_t)r;
    atomicAdd(s4 + 0, 1.0f);
    s4[1] = c.y; s4[2] = c.z; s4[3] = c.w;
}

// Zero xyz of multi-point rows (plain-stored values raced).
__global__ void k3b_zero(float4* __restrict__ sums, int N) {
    int r = blockIdx.x * blockDim.x + threadIdx.x;
    if (r >= N) return;
    float4 s = sums[r];
    if (s.x > 1.5f) sums[r] = make_float4(s.x, 0.f, 0.f, 0.f);
}

// Re-accumulate xyz for multi-point rows (~0.1% of points).
__global__ void k3c_multi(const float4* __restrict__ coords,
                          const uint32_t* __restrict__ ranks,
                          float* __restrict__ sums, int N) {
    int i = blockIdx.x * blockDim.x + threadIdx.x;
    if (i >= N) return;
    uint32_t r = ranks[i];
    float* s4 = sums + 4u * (size_t)r;
    if (s4[0] > 1.5f) {
        float4 c = coords[i];
        atomicAdd(s4 + 1, c.y);
        atomicAdd(s4 + 2, c.z);
        atomicAdd(s4 + 3, c.w);
    }
}

// Rank-centric fused epilogue, one wave = 64 consecutive ranks.
// Computes P^T via mfma(A=W2T-frag, B=h-frag): D-frag then holds 4 CONSECUTIVE
// feature-cols per register group -> float4 gathers/stores.
//   D[g][cg]: rank-row = rows_base+16g+(lane&15), cols = 16cg+4*(lane>>4)+{0..3}.
__global__ __launch_bounds__(256) void k5_fused(
        const float4* __restrict__ features4,
        const uint32_t* __restrict__ inv,
        const float4* __restrict__ sums,
        const float* __restrict__ W1, const float* __restrict__ b1,
        const short* __restrict__ W2T, const float* __restrict__ b2,
        float4* __restrict__ out_feat4, float* __restrict__ out_cent, int N) {
    int lane = threadIdx.x & 63;
    int rows_base = blockIdx.x * 256 + (threadIdx.x >> 6) * 64;

    // own-rank centers output
    int my = rows_base + lane;
    if (my < N) {
        float4 s4 = sums[my];
        float ic = s4.x > 0.f ? 1.f / s4.x : 0.f;
        out_cent[3 * (size_t)my + 0] = s4.y * ic;
        out_cent[3 * (size_t)my + 1] = s4.z * ic;
        out_cent[3 * (size_t)my + 2] = s4.w * ic;
    }

    // centers + counts for the 16-row groups (h B-fragments)
    float4 sg4[4]; float scx[4], scy[4], scz[4];
    #pragma unroll
    for (int g = 0; g < 4; ++g) {
        int rg = rows_base + (g << 4) + (lane & 15);
        sg4[g] = sums[rg < N ? rg : N - 1];
        float ic = sg4[g].x > 0.f ? 1.f / sg4[g].x : 0.f;
        scx[g] = sg4[g].y * ic; scy[g] = sg4[g].z * ic; scz[g] = sg4[g].w * ic;
    }

    f32x4 acc[4][4];
    #pragma unroll
    for (int cg = 0; cg < 4; ++cg) {
        float4 bv = ((const float4*)b2)[(cg << 2) + (lane >> 4)];
        #pragma unroll
        for (int g = 0; g < 4; ++g)
            acc[g][cg] = (f32x4){bv.x, bv.y, bv.z, bv.w};
    }

    #pragma unroll
    for (int s = 0; s < 2; ++s) {
        int kb = s * 32 + ((lane >> 4) << 3);
        float4 tx0 = *(const float4*)(W1 + kb),       tx1 = *(const float4*)(W1 + kb + 4);
        float4 ty0 = *(const float4*)(W1 + 64 + kb),  ty1 = *(const float4*)(W1 + 64 + kb + 4);
        float4 tz0 = *(const float4*)(W1 + 128 + kb), tz1 = *(const float4*)(W1 + 128 + kb + 4);
        float4 tb0 = *(const float4*)(b1 + kb),       tb1 = *(const float4*)(b1 + kb + 4);
        float w1x[8] = {tx0.x, tx0.y, tx0.z, tx0.w, tx1.x, tx1.y, tx1.z, tx1.w};
        float w1y[8] = {ty0.x, ty0.y, ty0.z, ty0.w, ty1.x, ty1.y, ty1.z, ty1.w};
        float w1z[8] = {tz0.x, tz0.y, tz0.z, tz0.w, tz1.x, tz1.y, tz1.z, tz1.w};
        float b1v[8] = {tb0.x, tb0.y, tb0.z, tb0.w, tb1.x, tb1.y, tb1.z, tb1.w};

        short8 afrag[4];   // W2T A-fragments: A[col=lane&15 (+16cg)][k]
        #pragma unroll
        for (int cg = 0; cg < 4; ++cg) {
            int col = (cg << 4) | (lane & 15);
            afrag[cg] = *(const short8*)(W2T + col * 64 + kb);
        }

        #pragma unroll
        for (int g = 0; g < 4; ++g) {
            short8 hf;   // h B-fragment: B[k][row=lane&15 (+16g)]
            #pragma unroll
            for (int j = 0; j < 8; ++j) {
                float h = fmaf(scz[g], w1z[j], fmaf(scy[g], w1y[j], fmaf(scx[g], w1x[j], b1v[j])));
                hf[j] = f2bf(fmaxf(h, 0.0f));
            }
            #pragma unroll
            for (int cg = 0; cg < 4; ++cg)
                acc[g][cg] = __builtin_amdgcn_mfma_f32_16x16x32_bf16(afrag[cg], hf, acc[g][cg], 0, 0, 0);
        }
    }

    // Epilogue: float4 per lane per (g,cg). cnt predicate {0: zero, 1: +feat, >1: pos only}.
    #pragma unroll
    for (int g = 0; g < 4; ++g) {
        int gr = rows_base + (g << 4) + (lane & 15);
        if (gr >= N) continue;
        float cnt = sg4[g].x;
        float4 v[4];
        #pragma unroll
        for (int cg = 0; cg < 4; ++cg)
            v[cg] = make_float4(acc[g][cg][0], acc[g][cg][1], acc[g][cg][2], acc[g][cg][3]);
        if (cnt == 0.0f) {
            #pragma unroll
            for (int cg = 0; cg < 4; ++cg) v[cg] = make_float4(0.f, 0.f, 0.f, 0.f);
        } else if (cnt == 1.0f) {
            size_t fb = (size_t)inv[gr] * 16 + (lane >> 4);
            #pragma unroll
            for (int cg = 0; cg < 4; ++cg) {
                float4 f = features4[fb + (cg << 2)];
                v[cg].x += f.x; v[cg].y += f.y; v[cg].z += f.z; v[cg].w += f.w;
            }
        }
        size_t ob = (size_t)gr * 16 + (lane >> 4);
        #pragma unroll
        for (int cg = 0; cg < 4; ++cg)
            out_feat4[ob + (cg << 2)] = v[cg];
    }
}

// Multi-point voxels: atomic accumulate f/c on top of pos (rare).
__global__ __launch_bounds__(256) void k5b_multi(
        const float* __restrict__ features, const uint32_t* __restrict__ ranks,
        const float4* __restrict__ sums, float* __restrict__ out_feat, int N) {
    int i = blockIdx.x * blockDim.x + threadIdx.x;
    if (i >= N) return;
    uint32_t r = ranks[i];
    float cnt = sums[r].x;
    if (cnt > 1.5f) {
        float iv = 1.0f / cnt;
        const float* frow = features + (size_t)i * 64;
        float* orow = out_feat + (size_t)r * 64;
        #pragma unroll 1
        for (int q = 0; q < 64; ++q) atomicAdd(&orow[q], frow[q] * iv);
    }
}

__global__ void k6_offsets(const uint32_t* __restrict__ bscan, float* __restrict__ out_off) {
    int t = threadIdx.x;
    if (t < 5) {
        uint32_t v;
        if (t == 0)      v = 0u;
        else if (t == 4) v = bscan[16384];
        else             v = bscan[(uint32_t)t << 12];   // block of key b<<27 (word b<<22)
        out_off[t] = (float)v;
    }
}

extern "C" void kernel_launch(void* const* d_in, const int* in_sizes, int n_in,
                              void* d_out, int out_size, void* d_ws, size_t ws_size,
                              hipStream_t stream) {
    const float4* coords = (const float4*)d_in[0];
    const float*  feats  = (const float*)d_in[1];
    const float*  W1 = (const float*)d_in[2];
    const float*  b1 = (const float*)d_in[3];
    const float*  W2 = (const float*)d_in[4];
    const float*  b2 = (const float*)d_in[5];
    int N = in_sizes[0] / 4;

    char* ws = (char*)d_ws;
    uint32_t* bitmap = (uint32_t*)ws;                                  // 64 MB
    uint16_t* scan8  = (uint16_t*)(ws + (1u << 26));                   // 4 MB
    uint32_t* bsum   = (uint32_t*)(ws + (1u << 26) + (1u << 22));      // 64 KB
    uint32_t* bscan  = bsum + NBLK;                                    // 16385 u32
    size_t off = (size_t)(1u << 26) + (1u << 22) + (size_t)NBLK * 4 + (size_t)(NBLK + 1) * 4;
    off = (off + 15) & ~(size_t)15;
    uint32_t* ranks = (uint32_t*)(ws + off);                           // 4N
    size_t off2 = (off + (size_t)N * 4 + 15) & ~(size_t)15;
    float* sums = (float*)(ws + off2);                                 // 16N {cnt,x,y,z}
    size_t off3 = off2 + (size_t)N * 16;
    uint32_t* inv = (uint32_t*)(ws + off3);                            // 4N rank->point
    size_t off4 = (off3 + (size_t)N * 4 + 15) & ~(size_t)15;
    short* W2T = (short*)(ws + off4);                                  // 8 KB bf16 W2^T

    float* out_feat = (float*)d_out;
    float* out_cent = out_feat + (size_t)N * 64;
    float* out_sp   = out_cent + (size_t)N * 3;
    float* out_off  = out_sp + N;

    hipMemsetAsync(bitmap, 0, (size_t)NWORDS * 4u, stream);
    hipMemsetAsync(sums, 0, (size_t)N * 16u, stream);

    int nb = (N + 255) / 256;
    k0_w2t<<<16, 256, 0, stream>>>(W2, W2T);
    k1_keys<<<nb, 256, 0, stream>>>(coords, bitmap, N);
    k2a_blockscan<<<NBLK, 256, 0, stream>>>((const uint4*)bitmap, scan8, bsum);
    k2b_topscan<<<1, 1024, 0, stream>>>(bsum, bscan);
    k3a_rank<<<nb, 256, 0, stream>>>(coords, ranks, bitmap, scan8, bscan, sums, inv, out_sp, N);
    k3b_zero<<<nb, 256, 0, stream>>>((float4*)sums, N);
    k3c_multi<<<nb, 256, 0, stream>>>(coords, ranks, sums, N);
    k5_fused<<<nb, 256, 0, stream>>>((const float4*)feats, inv, (const float4*)sums,
                                     W1, b1, W2T, b2, (float4*)out_feat, out_cent, N);
    k5b_multi<<<nb, 256, 0, stream>>>(feats, ranks, (const float4*)sums, out_feat, N);
    k6_offsets<<<1, 64, 0, stream>>>(bscan, out_off);
}

// Round 5
// 347.060 us; speedup vs baseline: 1.8033x; 1.0198x over previous
//
#include <hip/hip_runtime.h>
#include <stdint.h>

// Superpoint pooling via 29-bit key bitmap + prefix-popcount ranking.
// key = batch(2b)|qx(9b)|qy(9b)|qz(9b); numeric order == lex order, so exclusive
// prefix popcount over the presence bitmap == jnp.unique sorted rank.
// R5: NT output stores (preserve L3 for feature gather); 4-word popcount
// granularity (16B rank gather); compact multi-slot scratch kills 2 passes.

static constexpr uint32_t NWORDS = 1u << 24;        // 2^29 bits / 32
static constexpr uint32_t NBLK   = NWORDS / 1024;   // 16384 scan blocks
static constexpr uint32_t MCAP   = 65536;           // multi-voxel slot capacity

typedef __attribute__((ext_vector_type(8))) short short8;
typedef __attribute__((ext_vector_type(4))) float f32x4;

__device__ __forceinline__ short f2bf(float x) {
    union { float f; uint32_t u; } v; v.f = x;
    uint32_t u = v.u;
    uint32_t r = (u + 0x7FFFu + ((u >> 16) & 1u)) >> 16;   // RNE
    return (short)r;
}

__device__ __forceinline__ uint32_t point_key(float4 c) {
    uint32_t b  = (uint32_t)(int)c.x;
    uint32_t qx = (uint32_t)(int)floorf(c.y / 0.1f);
    uint32_t qy = (uint32_t)(int)floorf(c.z / 0.1f);
    uint32_t qz = (uint32_t)(int)floorf(c.w / 0.1f);
    return (b << 27) | (qx << 18) | (qy << 9) | qz;
}

// W2 -> bf16, transposed: W2T[col*64+k] = bf16(W2[k*64+col]).
__global__ void k0_w2t(const float* __restrict__ W2, short* __restrict__ W2T) {
    int t = blockIdx.x * 256 + threadIdx.x;
    if (t < 4096) {
        int col = t >> 6, k = t & 63;
        W2T[col * 64 + k] = f2bf(W2[k * 64 + col]);
    }
}

__global__ void k1_keys(const float4* __restrict__ coords, uint32_t* __restrict__ bitmap, int N) {
    int i = blockIdx.x * blockDim.x + threadIdx.x;
    if (i >= N) return;
    uint32_t key = point_key(coords[i]);
    atomicOr(&bitmap[key >> 5], 1u << (key & 31u));
}

// 1024 words/block, 256 threads, 4 words/thread via uint4, wave-shuffle scan.
// scan4[w>>2]: exclusive popcount prefix within block at 4-word granularity
// (max 255*128 = 32640, fits u16).
__global__ __launch_bounds__(256) void k2a_blockscan(
        const uint4* __restrict__ bm4, uint16_t* __restrict__ scan4,
        uint32_t* __restrict__ bsum) {
    int t = threadIdx.x;
    int lane = t & 63, wid = t >> 6;
    uint4 v = bm4[(size_t)blockIdx.x * 256 + t];
    uint32_t pc = __popc(v.x) + __popc(v.y) + __popc(v.z) + __popc(v.w);
    uint32_t sc = pc;
    #pragma unroll
    for (int off = 1; off < 64; off <<= 1) {
        uint32_t n = __shfl_up(sc, off);
        if (lane >= off) sc += n;
    }
    __shared__ uint32_t wt[4];
    if (lane == 63) wt[wid] = sc;
    __syncthreads();
    uint32_t wbase = 0;
    #pragma unroll
    for (int w = 0; w < 4; ++w) wbase += (w < wid) ? wt[w] : 0u;
    scan4[(size_t)blockIdx.x * 256 + t] = (uint16_t)(wbase + sc - pc);
    if (t == 255) bsum[blockIdx.x] = wbase + sc;
}

// Exclusive scan of 16384 block sums; bscan[16384] = total unique count U.
__global__ void k2b_topscan(const uint32_t* __restrict__ bsum, uint32_t* __restrict__ bscan) {
    __shared__ uint32_t s[1024];
    int t = threadIdx.x;
    uint32_t base = (uint32_t)t * 16u;
    const uint4* b4 = (const uint4*)(bsum + base);
    uint32_t sum = 0;
    #pragma unroll
    for (int k = 0; k < 4; ++k) { uint4 v = b4[k]; sum += v.x + v.y + v.z + v.w; }
    s[t] = sum;
    __syncthreads();
    for (int off = 1; off < 1024; off <<= 1) {
        uint32_t v = (t >= off) ? s[t - off] : 0u;
        __syncthreads();
        s[t] += v;
        __syncthreads();
    }
    uint32_t run = s[t] - sum;
    for (int k = 0; k < 16; ++k) { bscan[base + k] = run; run += bsum[base + k]; }
    if (t == 1023) bscan[16384] = run;
}

// Rank each point. ONE atomic (count) + plain 12B xyz store (exact for
// singletons). Second arrival of a voxel allocates a compact multi slot.
__global__ void k3a_rank(const float4* __restrict__ coords,
                         uint32_t* __restrict__ ranks,
                         const uint32_t* __restrict__ bitmap,
                         const uint16_t* __restrict__ scan4,
                         const uint32_t* __restrict__ bscan,
                         float* __restrict__ sums,      // [N][4] = {count, x, y, z}
                         uint32_t* __restrict__ inv,    // rank -> point
                         uint32_t* __restrict__ slotmap,
                         uint32_t* __restrict__ mctr,
                         float* __restrict__ out_sp, int N) {
    int i = blockIdx.x * blockDim.x + threadIdx.x;
    if (i >= N) return;
    float4 c = coords[i];
    uint32_t key = point_key(c);
    uint32_t w = key >> 5, bit = key & 31u;
    uint4 q = *(const uint4*)(bitmap + (w & ~3u));
    uint32_t wd[4] = {q.x, q.y, q.z, q.w};
    uint32_t idx = w & 3u;
    uint32_t r = bscan[w >> 10] + (uint32_t)scan4[w >> 2];
    uint32_t cur = 0;
    #pragma unroll
    for (uint32_t j = 0; j < 4; ++j) {
        r += (j < idx) ? __popc(wd[j]) : 0u;
        cur = (j == idx) ? wd[j] : cur;
    }
    r += __popc(cur & ((1u << bit) - 1u));
    ranks[i] = r;
    inv[r] = (uint32_t)i;
    __builtin_nontemporal_store((float)r, out_sp + i);
    float* s4 = sums + 4u * (size_t)r;
    float old = atomicAdd(s4 + 0, 1.0f);
    s4[1] = c.y; s4[2] = c.z; s4[3] = c.w;
    if (old == 1.0f) {                       // exactly one allocator per multi voxel
        uint32_t slot = atomicAdd(mctr, 1u);
        if (slot < MCAP) slotmap[r] = slot + 1u;
    }
}

// Fixup for multi voxels (~0.1% of points do work): accumulate xyz into msum
// and features/c into mfeat, in compact slot space. Runs BEFORE k5.
__global__ void k3fix(const float4* __restrict__ coords,
                      const float* __restrict__ features,
                      const uint32_t* __restrict__ ranks,
                      const uint32_t* __restrict__ slotmap,
                      const float4* __restrict__ sums,
                      float* __restrict__ msum,          // [MCAP][4]
                      float* __restrict__ mfeat, int N) { // [MCAP][64]
    int i = blockIdx.x * blockDim.x + threadIdx.x;
    if (i >= N) return;
    uint32_t r = ranks[i];
    uint32_t sl = slotmap[r];
    if (sl == 0) return;
    sl -= 1u;
    float cnt = sums[r].x;
    float4 c = coords[i];
    float* m = msum + 4u * (size_t)sl;
    atomicAdd(m + 0, c.y);
    atomicAdd(m + 1, c.z);
    atomicAdd(m + 2, c.w);
    float iv = 1.0f / cnt;
    const float* frow = features + (size_t)i * 64;
    float* orow = mfeat + (size_t)sl * 64;
    #pragma unroll 1
    for (int qq = 0; qq < 64; ++qq) atomicAdd(&orow[qq], frow[qq] * iv);
}

// Rank-centric fused epilogue, one wave = 64 consecutive ranks.
// P^T via mfma(A=W2T-frag, B=h-frag): D[g][cg] rank-row = rows_base+16g+(lane&15),
// cols = 16cg+4*(lane>>4)+{0..3} -> float4 gathers + NT float4 stores.
__global__ __launch_bounds__(256) void k5_fused(
        const f32x4* __restrict__ features4,
        const uint32_t* __restrict__ inv,
        const float4* __restrict__ sums,
        const uint32_t* __restrict__ slotmap,
        const float4* __restrict__ msum,
        const f32x4* __restrict__ mfeat4,
        const float* __restrict__ W1, const float* __restrict__ b1,
        const short* __restrict__ W2T, const float* __restrict__ b2,
        f32x4* __restrict__ out_feat4, float* __restrict__ out_cent, int N) {
    int lane = threadIdx.x & 63;
    int rows_base = blockIdx.x * 256 + (threadIdx.x >> 6) * 64;

    // own-rank centers output (multi rows: centers from msum)
    int my = rows_base + lane;
    if (my < N) {
        float4 s4 = sums[my];
        float sx = s4.y, sy = s4.z, sz = s4.w;
        if (s4.x > 1.5f) {
            float4 m = msum[slotmap[my] - 1u];
            sx = m.x; sy = m.y; sz = m.z;
        }
        float ic = s4.x > 0.f ? 1.f / s4.x : 0.f;
        __builtin_nontemporal_store(sx * ic, out_cent + 3 * (size_t)my + 0);
        __builtin_nontemporal_store(sy * ic, out_cent + 3 * (size_t)my + 1);
        __builtin_nontemporal_store(sz * ic, out_cent + 3 * (size_t)my + 2);
    }

    // centers + counts for the 16-row groups (h B-fragments)
    float cntg[4], scx[4], scy[4], scz[4];
    #pragma unroll
    for (int g = 0; g < 4; ++g) {
        int rg = rows_base + (g << 4) + (lane & 15);
        int rgc = rg < N ? rg : N - 1;
        float4 sg = sums[rgc];
        cntg[g] = sg.x;
        float sx = sg.y, sy = sg.z, sz = sg.w;
        if (sg.x > 1.5f) {
            float4 m = msum[slotmap[rgc] - 1u];
            sx = m.x; sy = m.y; sz = m.z;
        }
        float ic = sg.x > 0.f ? 1.f / sg.x : 0.f;
        scx[g] = sx * ic; scy[g] = sy * ic; scz[g] = sz * ic;
    }

    f32x4 acc[4][4];
    #pragma unroll
    for (int cg = 0; cg < 4; ++cg) {
        f32x4 bv = ((const f32x4*)b2)[(cg << 2) + (lane >> 4)];
        #pragma unroll
        for (int g = 0; g < 4; ++g)
            acc[g][cg] = bv;
    }

    #pragma unroll
    for (int s = 0; s < 2; ++s) {
        int kb = s * 32 + ((lane >> 4) << 3);
        float4 tx0 = *(const float4*)(W1 + kb),       tx1 = *(const float4*)(W1 + kb + 4);
        float4 ty0 = *(const float4*)(W1 + 64 + kb),  ty1 = *(const float4*)(W1 + 64 + kb + 4);
        float4 tz0 = *(const float4*)(W1 + 128 + kb), tz1 = *(const float4*)(W1 + 128 + kb + 4);
        float4 tb0 = *(const float4*)(b1 + kb),       tb1 = *(const float4*)(b1 + kb + 4);
        float w1x[8] = {tx0.x, tx0.y, tx0.z, tx0.w, tx1.x, tx1.y, tx1.z, tx1.w};
        float w1y[8] = {ty0.x, ty0.y, ty0.z, ty0.w, ty1.x, ty1.y, ty1.z, ty1.w};
        float w1z[8] = {tz0.x, tz0.y, tz0.z, tz0.w, tz1.x, tz1.y, tz1.z, tz1.w};
        float b1v[8] = {tb0.x, tb0.y, tb0.z, tb0.w, tb1.x, tb1.y, tb1.z, tb1.w};

        short8 afrag[4];   // W2T A-fragments: A[col=lane&15 (+16cg)][k]
        #pragma unroll
        for (int cg = 0; cg < 4; ++cg) {
            int col = (cg << 4) | (lane & 15);
            afrag[cg] = *(const short8*)(W2T + col * 64 + kb);
        }

        #pragma unroll
        for (int g = 0; g < 4; ++g) {
            short8 hf;   // h B-fragment: B[k][row=lane&15 (+16g)]
            #pragma unroll
            for (int j = 0; j < 8; ++j) {
                float h = fmaf(scz[g], w1z[j], fmaf(scy[g], w1y[j], fmaf(scx[g], w1x[j], b1v[j])));
                hf[j] = f2bf(fmaxf(h, 0.0f));
            }
            #pragma unroll
            for (int cg = 0; cg < 4; ++cg)
                acc[g][cg] = __builtin_amdgcn_mfma_f32_16x16x32_bf16(afrag[cg], hf, acc[g][cg], 0, 0, 0);
        }
    }

    // Epilogue: float4 per lane per (g,cg); NT stores.
    #pragma unroll
    for (int g = 0; g < 4; ++g) {
        int gr = rows_base + (g << 4) + (lane & 15);
        if (gr >= N) continue;
        float cnt = cntg[g];
        f32x4 v[4];
        #pragma unroll
        for (int cg = 0; cg < 4; ++cg) v[cg] = acc[g][cg];
        if (cnt == 0.0f) {
            #pragma unroll
            for (int cg = 0; cg < 4; ++cg) v[cg] = (f32x4){0.f, 0.f, 0.f, 0.f};
        } else if (cnt == 1.0f) {
            size_t fb = (size_t)inv[gr] * 16 + (lane >> 4);
            #pragma unroll
            for (int cg = 0; cg < 4; ++cg) v[cg] += features4[fb + (cg << 2)];
        } else {
            size_t mb = (size_t)(slotmap[gr] - 1u) * 16 + (lane >> 4);
            #pragma unroll
            for (int cg = 0; cg < 4; ++cg) v[cg] += mfeat4[mb + (cg << 2)];
        }
        size_t ob = (size_t)gr * 16 + (lane >> 4);
        #pragma unroll
        for (int cg = 0; cg < 4; ++cg)
            __builtin_nontemporal_store(v[cg], out_feat4 + ob + (cg << 2));
    }
}

__global__ void k6_offsets(const uint32_t* __restrict__ bscan, float* __restrict__ out_off) {
    int t = threadIdx.x;
    if (t < 5) {
        uint32_t v;
        if (t == 0)      v = 0u;
        else if (t == 4) v = bscan[16384];
        else             v = bscan[(uint32_t)t << 12];   // block of key b<<27 (word b<<22)
        out_off[t] = (float)v;
    }
}

extern "C" void kernel_launch(void* const* d_in, const int* in_sizes, int n_in,
                              void* d_out, int out_size, void* d_ws, size_t ws_size,
                              hipStream_t stream) {
    const float4* coords = (const float4*)d_in[0];
    const float*  feats  = (const float*)d_in[1];
    const float*  W1 = (const float*)d_in[2];
    const float*  b1 = (const float*)d_in[3];
    const float*  W2 = (const float*)d_in[4];
    const float*  b2 = (const float*)d_in[5];
    int N = in_sizes[0] / 4;

    char* ws = (char*)d_ws;
    size_t o = 0;
    uint32_t* bitmap = (uint32_t*)(ws + o); o += (size_t)NWORDS * 4;        // 64 MB
    uint16_t* scan4  = (uint16_t*)(ws + o); o += (size_t)(NWORDS / 4) * 2;  // 8 MB
    uint32_t* bsum   = (uint32_t*)(ws + o); o += (size_t)NBLK * 4;          // 64 KB
    uint32_t* bscan  = (uint32_t*)(ws + o); o += (size_t)(NBLK + 1) * 4;
    o = (o + 15) & ~(size_t)15;
    uint32_t* ranks  = (uint32_t*)(ws + o); o += (size_t)N * 4;
    o = (o + 15) & ~(size_t)15;
    float*    sums   = (float*)(ws + o);    o += (size_t)N * 16;            // {cnt,x,y,z}
    uint32_t* inv    = (uint32_t*)(ws + o); o += (size_t)N * 4;
    o = (o + 15) & ~(size_t)15;
    short*    W2T    = (short*)(ws + o);    o += 8192;
    // ---- multi region (single memset) ----
    size_t multi_base = o;
    uint32_t* slotmap = (uint32_t*)(ws + o); o += (size_t)N * 4;
    uint32_t* mctr    = (uint32_t*)(ws + o); o += 16;
    float*    msum    = (float*)(ws + o);    o += (size_t)MCAP * 16;
    float*    mfeat   = (float*)(ws + o);    o += (size_t)MCAP * 256;
    size_t multi_size = o - multi_base;

    float* out_feat = (float*)d_out;
    float* out_cent = out_feat + (size_t)N * 64;
    float* out_sp   = out_cent + (size_t)N * 3;
    float* out_off  = out_sp + N;

    hipMemsetAsync(bitmap, 0, (size_t)NWORDS * 4, stream);
    hipMemsetAsync(sums, 0, (size_t)N * 16, stream);
    hipMemsetAsync(ws + multi_base, 0, multi_size, stream);

    int nb = (N + 255) / 256;
    k0_w2t<<<16, 256, 0, stream>>>(W2, W2T);
    k1_keys<<<nb, 256, 0, stream>>>(coords, bitmap, N);
    k2a_blockscan<<<NBLK, 256, 0, stream>>>((const uint4*)bitmap, scan4, bsum);
    k2b_topscan<<<1, 1024, 0, stream>>>(bsum, bscan);
    k3a_rank<<<nb, 256, 0, stream>>>(coords, ranks, bitmap, scan4, bscan, sums, inv,
                                     slotmap, mctr, out_sp, N);
    k3fix<<<nb, 256, 0, stream>>>(coords, feats, ranks, slotmap, (const float4*)sums,
                                  msum, mfeat, N);
    k5_fused<<<nb, 256, 0, stream>>>((const f32x4*)feats, inv, (const float4*)sums,
                                     slotmap, (const float4*)msum, (const f32x4*)mfeat,
                                     W1, b1, W2T, b2, (f32x4*)out_feat, out_cent, N);
    k6_offsets<<<1, 64, 0, stream>>>(bscan, out_off);
}

// Round 6
// 327.340 us; speedup vs baseline: 1.9119x; 1.0602x over previous
//
#include <hip/hip_runtime.h>
#include <stdint.h>

// Superpoint pooling via 29-bit key bitmap + prefix-popcount ranking.
// key = batch(2b)|qx(9b)|qy(9b)|qz(9b); numeric order == lex order, so exclusive
// prefix popcount over the presence bitmap == jnp.unique sorted rank.
// R6: plain stores (NT regressed: partial-line writes); k5 issues all feature
// gathers EARLY and folds them into acc init so MFMA hides gather latency.

static constexpr uint32_t NWORDS = 1u << 24;        // 2^29 bits / 32
static constexpr uint32_t NBLK   = NWORDS / 1024;   // 16384 scan blocks
static constexpr uint32_t MCAP   = 65536;           // multi-voxel slot capacity

typedef __attribute__((ext_vector_type(8))) short short8;
typedef __attribute__((ext_vector_type(4))) float f32x4;

__device__ __forceinline__ short f2bf(float x) {
    union { float f; uint32_t u; } v; v.f = x;
    uint32_t u = v.u;
    uint32_t r = (u + 0x7FFFu + ((u >> 16) & 1u)) >> 16;   // RNE
    return (short)r;
}

__device__ __forceinline__ uint32_t point_key(float4 c) {
    uint32_t b  = (uint32_t)(int)c.x;
    uint32_t qx = (uint32_t)(int)floorf(c.y / 0.1f);
    uint32_t qy = (uint32_t)(int)floorf(c.z / 0.1f);
    uint32_t qz = (uint32_t)(int)floorf(c.w / 0.1f);
    return (b << 27) | (qx << 18) | (qy << 9) | qz;
}

// W2 -> bf16, transposed: W2T[col*64+k] = bf16(W2[k*64+col]).
__global__ void k0_w2t(const float* __restrict__ W2, short* __restrict__ W2T) {
    int t = blockIdx.x * 256 + threadIdx.x;
    if (t < 4096) {
        int col = t >> 6, k = t & 63;
        W2T[col * 64 + k] = f2bf(W2[k * 64 + col]);
    }
}

__global__ void k1_keys(const float4* __restrict__ coords, uint32_t* __restrict__ bitmap, int N) {
    int i = blockIdx.x * blockDim.x + threadIdx.x;
    if (i >= N) return;
    uint32_t key = point_key(coords[i]);
    atomicOr(&bitmap[key >> 5], 1u << (key & 31u));
}

// 1024 words/block, 256 threads, 4 words/thread via uint4, wave-shuffle scan.
// scan4[w>>2]: exclusive popcount prefix within block at 4-word granularity
// (max 255*128 = 32640, fits u16).
__global__ __launch_bounds__(256) void k2a_blockscan(
        const uint4* __restrict__ bm4, uint16_t* __restrict__ scan4,
        uint32_t* __restrict__ bsum) {
    int t = threadIdx.x;
    int lane = t & 63, wid = t >> 6;
    uint4 v = bm4[(size_t)blockIdx.x * 256 + t];
    uint32_t pc = __popc(v.x) + __popc(v.y) + __popc(v.z) + __popc(v.w);
    uint32_t sc = pc;
    #pragma unroll
    for (int off = 1; off < 64; off <<= 1) {
        uint32_t n = __shfl_up(sc, off);
        if (lane >= off) sc += n;
    }
    __shared__ uint32_t wt[4];
    if (lane == 63) wt[wid] = sc;
    __syncthreads();
    uint32_t wbase = 0;
    #pragma unroll
    for (int w = 0; w < 4; ++w) wbase += (w < wid) ? wt[w] : 0u;
    scan4[(size_t)blockIdx.x * 256 + t] = (uint16_t)(wbase + sc - pc);
    if (t == 255) bsum[blockIdx.x] = wbase + sc;
}

// Exclusive scan of 16384 block sums; bscan[16384] = total unique count U.
__global__ void k2b_topscan(const uint32_t* __restrict__ bsum, uint32_t* __restrict__ bscan) {
    __shared__ uint32_t s[1024];
    int t = threadIdx.x;
    uint32_t base = (uint32_t)t * 16u;
    const uint4* b4 = (const uint4*)(bsum + base);
    uint32_t sum = 0;
    #pragma unroll
    for (int k = 0; k < 4; ++k) { uint4 v = b4[k]; sum += v.x + v.y + v.z + v.w; }
    s[t] = sum;
    __syncthreads();
    for (int off = 1; off < 1024; off <<= 1) {
        uint32_t v = (t >= off) ? s[t - off] : 0u;
        __syncthreads();
        s[t] += v;
        __syncthreads();
    }
    uint32_t run = s[t] - sum;
    for (int k = 0; k < 16; ++k) { bscan[base + k] = run; run += bsum[base + k]; }
    if (t == 1023) bscan[16384] = run;
}

// Rank each point. ONE atomic (count) + plain 12B xyz store (exact for
// singletons). Second arrival of a voxel allocates a compact multi slot.
__global__ void k3a_rank(const float4* __restrict__ coords,
                         uint32_t* __restrict__ ranks,
                         const uint32_t* __restrict__ bitmap,
                         const uint16_t* __restrict__ scan4,
                         const uint32_t* __restrict__ bscan,
                         float* __restrict__ sums,      // [N][4] = {count, x, y, z}
                         uint32_t* __restrict__ inv,    // rank -> point
                         uint32_t* __restrict__ slotmap,
                         uint32_t* __restrict__ mctr,
                         float* __restrict__ out_sp, int N) {
    int i = blockIdx.x * blockDim.x + threadIdx.x;
    if (i >= N) return;
    float4 c = coords[i];
    uint32_t key = point_key(c);
    uint32_t w = key >> 5, bit = key & 31u;
    uint4 q = *(const uint4*)(bitmap + (w & ~3u));
    uint32_t wd[4] = {q.x, q.y, q.z, q.w};
    uint32_t idx = w & 3u;
    uint32_t r = bscan[w >> 10] + (uint32_t)scan4[w >> 2];
    uint32_t cur = 0;
    #pragma unroll
    for (uint32_t j = 0; j < 4; ++j) {
        r += (j < idx) ? __popc(wd[j]) : 0u;
        cur = (j == idx) ? wd[j] : cur;
    }
    r += __popc(cur & ((1u << bit) - 1u));
    ranks[i] = r;
    inv[r] = (uint32_t)i;
    out_sp[i] = (float)r;
    float* s4 = sums + 4u * (size_t)r;
    float old = atomicAdd(s4 + 0, 1.0f);
    s4[1] = c.y; s4[2] = c.z; s4[3] = c.w;
    if (old == 1.0f) {                       // exactly one allocator per multi voxel
        uint32_t slot = atomicAdd(mctr, 1u);
        if (slot < MCAP) slotmap[r] = slot + 1u;
    }
}

// Fixup for multi voxels (~0.1% of points do work): accumulate xyz into msum
// and features/c into mfeat, in compact slot space. Runs BEFORE k5.
__global__ void k3fix(const float4* __restrict__ coords,
                      const float* __restrict__ features,
                      const uint32_t* __restrict__ ranks,
                      const uint32_t* __restrict__ slotmap,
                      const float4* __restrict__ sums,
                      float* __restrict__ msum,          // [MCAP][4]
                      float* __restrict__ mfeat, int N) { // [MCAP][64]
    int i = blockIdx.x * blockDim.x + threadIdx.x;
    if (i >= N) return;
    uint32_t r = ranks[i];
    uint32_t sl = slotmap[r];
    if (sl == 0) return;
    sl -= 1u;
    float cnt = sums[r].x;
    float4 c = coords[i];
    float* m = msum + 4u * (size_t)sl;
    atomicAdd(m + 0, c.y);
    atomicAdd(m + 1, c.z);
    atomicAdd(m + 2, c.w);
    float iv = 1.0f / cnt;
    const float* frow = features + (size_t)i * 64;
    float* orow = mfeat + (size_t)sl * 64;
    #pragma unroll 1
    for (int qq = 0; qq < 64; ++qq) atomicAdd(&orow[qq], frow[qq] * iv);
}

// Rank-centric fused epilogue, one wave = 64 consecutive ranks.
// P^T via mfma(A=W2T-frag, B=h-frag): D[g][cg] rank-row = rows_base+16g+(lane&15),
// cols = 16cg+4*(lane>>4)+{0..3}. Feature gathers are issued FIRST (unconditional,
// clamped index) and folded into acc init; the W1/h/MFMA section runs under them.
__global__ __launch_bounds__(256) void k5_fused(
        const f32x4* __restrict__ features4,
        const uint32_t* __restrict__ inv,
        const float4* __restrict__ sums,
        const uint32_t* __restrict__ slotmap,
        const float4* __restrict__ msum,
        const f32x4* __restrict__ mfeat4,
        const float* __restrict__ W1, const float* __restrict__ b1,
        const short* __restrict__ W2T, const float* __restrict__ b2,
        f32x4* __restrict__ out_feat4, float* __restrict__ out_cent, int N) {
    int lane = threadIdx.x & 63;
    int rows_base = blockIdx.x * 256 + (threadIdx.x >> 6) * 64;

    // ---- sequential metadata loads, then EARLY random feature gathers ----
    float4 sg4[4]; float cntg[4]; uint32_t invg[4];
    #pragma unroll
    for (int g = 0; g < 4; ++g) {
        int rg = rows_base + (g << 4) + (lane & 15);
        int rgc = rg < N ? rg : N - 1;
        sg4[g] = sums[rgc];
        cntg[g] = sg4[g].x;
        invg[g] = inv[rgc];
    }
    f32x4 acc[4][4];
    #pragma unroll
    for (int g = 0; g < 4; ++g) {
        uint32_t sel = (cntg[g] > 0.f) ? invg[g] : 0u;   // cnt==0: harmless row 0
        size_t fb = (size_t)sel * 16 + (lane >> 4);
        #pragma unroll
        for (int cg = 0; cg < 4; ++cg) acc[g][cg] = features4[fb + (cg << 2)];
    }
    // acc = b2 + (cnt==1 ? feat : 0); non-singleton feat discarded here
    #pragma unroll
    for (int cg = 0; cg < 4; ++cg) {
        f32x4 bv = ((const f32x4*)b2)[(cg << 2) + (lane >> 4)];
        #pragma unroll
        for (int g = 0; g < 4; ++g)
            acc[g][cg] = (cntg[g] == 1.0f) ? (acc[g][cg] + bv) : bv;
    }

    // centers for the 16-row groups (h B-fragments); multi rows from msum
    float scx[4], scy[4], scz[4];
    #pragma unroll
    for (int g = 0; g < 4; ++g) {
        int rg = rows_base + (g << 4) + (lane & 15);
        int rgc = rg < N ? rg : N - 1;
        float sx = sg4[g].y, sy = sg4[g].z, sz = sg4[g].w;
        if (cntg[g] > 1.5f) {
            float4 m = msum[slotmap[rgc] - 1u];
            sx = m.x; sy = m.y; sz = m.z;
        }
        float ic = cntg[g] > 0.f ? 1.f / cntg[g] : 0.f;
        scx[g] = sx * ic; scy[g] = sy * ic; scz[g] = sz * ic;
    }

    #pragma unroll
    for (int s = 0; s < 2; ++s) {
        int kb = s * 32 + ((lane >> 4) << 3);
        float4 tx0 = *(const float4*)(W1 + kb),       tx1 = *(const float4*)(W1 + kb + 4);
        float4 ty0 = *(const float4*)(W1 + 64 + kb),  ty1 = *(const float4*)(W1 + 64 + kb + 4);
        float4 tz0 = *(const float4*)(W1 + 128 + kb), tz1 = *(const float4*)(W1 + 128 + kb + 4);
        float4 tb0 = *(const float4*)(b1 + kb),       tb1 = *(const float4*)(b1 + kb + 4);
        float w1x[8] = {tx0.x, tx0.y, tx0.z, tx0.w, tx1.x, tx1.y, tx1.z, tx1.w};
        float w1y[8] = {ty0.x, ty0.y, ty0.z, ty0.w, ty1.x, ty1.y, ty1.z, ty1.w};
        float w1z[8] = {tz0.x, tz0.y, tz0.z, tz0.w, tz1.x, tz1.y, tz1.z, tz1.w};
        float b1v[8] = {tb0.x, tb0.y, tb0.z, tb0.w, tb1.x, tb1.y, tb1.z, tb1.w};

        short8 afrag[4];   // W2T A-fragments: A[col=lane&15 (+16cg)][k]
        #pragma unroll
        for (int cg = 0; cg < 4; ++cg) {
            int col = (cg << 4) | (lane & 15);
            afrag[cg] = *(const short8*)(W2T + col * 64 + kb);
        }

        #pragma unroll
        for (int g = 0; g < 4; ++g) {
            short8 hf;   // h B-fragment: B[k][row=lane&15 (+16g)]
            #pragma unroll
            for (int j = 0; j < 8; ++j) {
                float h = fmaf(scz[g], w1z[j], fmaf(scy[g], w1y[j], fmaf(scx[g], w1x[j], b1v[j])));
                hf[j] = f2bf(fmaxf(h, 0.0f));
            }
            #pragma unroll
            for (int cg = 0; cg < 4; ++cg)
                acc[g][cg] = __builtin_amdgcn_mfma_f32_16x16x32_bf16(afrag[cg], hf, acc[g][cg], 0, 0, 0);
        }
    }

    // own-rank centers output (independent of MFMA; multi rows from msum)
    int my = rows_base + lane;
    if (my < N) {
        float4 s4 = sums[my];          // L1-hot (same 1KB as sg4)
        float sx = s4.y, sy = s4.z, sz = s4.w;
        if (s4.x > 1.5f) {
            float4 m = msum[slotmap[my] - 1u];
            sx = m.x; sy = m.y; sz = m.z;
        }
        float ic = s4.x > 0.f ? 1.f / s4.x : 0.f;
        out_cent[3 * (size_t)my + 0] = sx * ic;
        out_cent[3 * (size_t)my + 1] = sy * ic;
        out_cent[3 * (size_t)my + 2] = sz * ic;
    }

    // Epilogue: select + plain float4 stores (L2 merges the 4 cg-sectors).
    #pragma unroll
    for (int g = 0; g < 4; ++g) {
        int gr = rows_base + (g << 4) + (lane & 15);
        if (gr >= N) continue;
        float cnt = cntg[g];
        f32x4 v[4];
        #pragma unroll
        for (int cg = 0; cg < 4; ++cg) v[cg] = acc[g][cg];
        if (cnt == 0.0f) {
            #pragma unroll
            for (int cg = 0; cg < 4; ++cg) v[cg] = (f32x4){0.f, 0.f, 0.f, 0.f};
        } else if (cnt > 1.5f) {
            size_t mb = (size_t)(slotmap[gr] - 1u) * 16 + (lane >> 4);
            #pragma unroll
            for (int cg = 0; cg < 4; ++cg) v[cg] += mfeat4[mb + (cg << 2)];
        }
        size_t ob = (size_t)gr * 16 + (lane >> 4);
        #pragma unroll
        for (int cg = 0; cg < 4; ++cg)
            out_feat4[ob + (cg << 2)] = v[cg];
    }
}

__global__ void k6_offsets(const uint32_t* __restrict__ bscan, float* __restrict__ out_off) {
    int t = threadIdx.x;
    if (t < 5) {
        uint32_t v;
        if (t == 0)      v = 0u;
        else if (t == 4) v = bscan[16384];
        else             v = bscan[(uint32_t)t << 12];   // block of key b<<27 (word b<<22)
        out_off[t] = (float)v;
    }
}

extern "C" void kernel_launch(void* const* d_in, const int* in_sizes, int n_in,
                              void* d_out, int out_size, void* d_ws, size_t ws_size,
                              hipStream_t stream) {
    const float4* coords = (const float4*)d_in[0];
    const float*  feats  = (const float*)d_in[1];
    const float*  W1 = (const float*)d_in[2];
    const float*  b1 = (const float*)d_in[3];
    const float*  W2 = (const float*)d_in[4];
    const float*  b2 = (const float*)d_in[5];
    int N = in_sizes[0] / 4;

    char* ws = (char*)d_ws;
    size_t o = 0;
    uint32_t* bitmap = (uint32_t*)(ws + o); o += (size_t)NWORDS * 4;        // 64 MB
    uint16_t* scan4  = (uint16_t*)(ws + o); o += (size_t)(NWORDS / 4) * 2;  // 8 MB
    uint32_t* bsum   = (uint32_t*)(ws + o); o += (size_t)NBLK * 4;          // 64 KB
    uint32_t* bscan  = (uint32_t*)(ws + o); o += (size_t)(NBLK + 1) * 4;
    o = (o + 15) & ~(size_t)15;
    uint32_t* ranks  = (uint32_t*)(ws + o); o += (size_t)N * 4;
    o = (o + 15) & ~(size_t)15;
    float*    sums   = (float*)(ws + o);    o += (size_t)N * 16;            // {cnt,x,y,z}
    uint32_t* inv    = (uint32_t*)(ws + o); o += (size_t)N * 4;
    o = (o + 15) & ~(size_t)15;
    short*    W2T    = (short*)(ws + o);    o += 8192;
    // ---- multi region (single memset) ----
    size_t multi_base = o;
    uint32_t* slotmap = (uint32_t*)(ws + o); o += (size_t)N * 4;
    uint32_t* mctr    = (uint32_t*)(ws + o); o += 16;
    float*    msum    = (float*)(ws + o);    o += (size_t)MCAP * 16;
    float*    mfeat   = (float*)(ws + o);    o += (size_t)MCAP * 256;
    size_t multi_size = o - multi_base;

    float* out_feat = (float*)d_out;
    float* out_cent = out_feat + (size_t)N * 64;
    float* out_sp   = out_cent + (size_t)N * 3;
    float* out_off  = out_sp + N;

    hipMemsetAsync(bitmap, 0, (size_t)NWORDS * 4, stream);
    hipMemsetAsync(sums, 0, (size_t)N * 16, stream);
    hipMemsetAsync(ws + multi_base, 0, multi_size, stream);

    int nb = (N + 255) / 256;
    k0_w2t<<<16, 256, 0, stream>>>(W2, W2T);
    k1_keys<<<nb, 256, 0, stream>>>(coords, bitmap, N);
    k2a_blockscan<<<NBLK, 256, 0, stream>>>((const uint4*)bitmap, scan4, bsum);
    k2b_topscan<<<1, 1024, 0, stream>>>(bsum, bscan);
    k3a_rank<<<nb, 256, 0, stream>>>(coords, ranks, bitmap, scan4, bscan, sums, inv,
                                     slotmap, mctr, out_sp, N);
    k3fix<<<nb, 256, 0, stream>>>(coords, feats, ranks, slotmap, (const float4*)sums,
                                  msum, mfeat, N);
    k5_fused<<<nb, 256, 0, stream>>>((const f32x4*)feats, inv, (const float4*)sums,
                                     slotmap, (const float4*)msum, (const f32x4*)mfeat,
                                     W1, b1, W2T, b2, (f32x4*)out_feat, out_cent, N);
    k6_offsets<<<1, 64, 0, stream>>>(bscan, out_off);
}